// Round 9
// baseline (70.451 us; speedup 1.0000x reference)
//
#include <hip/hip_runtime.h>

#define NB 2
#define SQL 256
#define NH 16
#define HD 64
#define EMB 1024

typedef unsigned short ushortT;
typedef unsigned int uintT;
typedef __attribute__((ext_vector_type(8))) short bf16x8;
typedef __attribute__((ext_vector_type(4))) float f32x4;

// log2(e) / sqrt(EMBED): folded into Wq so softmax = 2^(q*k)
__device__ __constant__ float kQSCALE = 1.4426950408889634f / 32.0f;

__device__ __forceinline__ float fexp2(float x) { return __builtin_amdgcn_exp2f(x); }
__device__ __forceinline__ float frcp(float x)  { return __builtin_amdgcn_rcpf(x); }

__device__ __forceinline__ ushortT f2bf(float x) {
    uintT u = __float_as_uint(x);
    u += 0x7fffu + ((u >> 16) & 1u);        // RNE
    return (ushortT)(u >> 16);
}
// unpack 8 bf16 (element order = memory order) to f32
__device__ __forceinline__ void unpk8(uint4 u, float* f) {
    f[0] = __uint_as_float(u.x << 16); f[1] = __uint_as_float(u.x & 0xffff0000u);
    f[2] = __uint_as_float(u.y << 16); f[3] = __uint_as_float(u.y & 0xffff0000u);
    f[4] = __uint_as_float(u.z << 16); f[5] = __uint_as_float(u.z & 0xffff0000u);
    f[6] = __uint_as_float(u.w << 16); f[7] = __uint_as_float(u.w & 0xffff0000u);
}

// ---------------------------------------------------------------------------
// Kernel 0: out = bias broadcast; AO = 0.
// ---------------------------------------------------------------------------
__global__ __launch_bounds__(256) void init_kernel(
    const float* __restrict__ bo,
    float* __restrict__ AO,
    float* __restrict__ out)
{
    const int i = blockIdx.x * 256 + threadIdx.x;   // 131072 float4s
    const float4 b = ((const float4*)bo)[i & 255];
    ((float4*)out)[i] = b;
    ((float4*)AO)[i]  = make_float4(0.f, 0.f, 0.f, 0.f);
}

// ---------------------------------------------------------------------------
// Kernel 1: q/k/v projections -> bf16. TWO blocks per (n,s), each computing
// 32 of 64 e-outputs. Output element order [ns][e*16+h]. Wq pre-scaled.
// ---------------------------------------------------------------------------
__global__ __launch_bounds__(256) void qkv_kernel(
    const float* __restrict__ x,
    const float* __restrict__ Wq,
    const float* __restrict__ Wk,
    const float* __restrict__ Wv,
    ushortT* __restrict__ Q,
    ushortT* __restrict__ K,
    ushortT* __restrict__ V)
{
    __shared__ float wq[32 * 68];
    __shared__ float wk[32 * 68];
    __shared__ float wv[32 * 68];
    __shared__ float xs[16 * 68];

    const int tid  = threadIdx.x;
    const int ns   = blockIdx.x >> 1;
    const int half = blockIdx.x & 1;

    {
        const int h  = tid >> 4;
        const int d0 = (tid & 15) * 4;
        const float4 a = ((const float4*)(x + (size_t)ns * EMB))[tid];
        *(float4*)&xs[h * 68 + d0] = a;
    }
#pragma unroll
    for (int j = 0; j < 2; ++j) {
        const int f4 = j * 256 + tid;
        const int e  = f4 >> 4;
        const int d4 = f4 & 15;
        const int g  = half * 512 + f4;
        float4 a = ((const float4*)Wq)[g];
        a.x *= kQSCALE; a.y *= kQSCALE; a.z *= kQSCALE; a.w *= kQSCALE;
        *(float4*)&wq[e * 68 + d4 * 4] = a;
        *(float4*)&wk[e * 68 + d4 * 4] = ((const float4*)Wk)[g];
        *(float4*)&wv[e * 68 + d4 * 4] = ((const float4*)Wv)[g];
    }
    __syncthreads();

    const int el = tid >> 3;
    const int h0 = (tid & 7) * 2;

    float aq[2] = {0.f, 0.f}, ak[2] = {0.f, 0.f}, av[2] = {0.f, 0.f};

#pragma unroll
    for (int d4 = 0; d4 < 16; ++d4) {
        const float4 wqv = *(const float4*)&wq[el * 68 + d4 * 4];
        const float4 wkv = *(const float4*)&wk[el * 68 + d4 * 4];
        const float4 wvv = *(const float4*)&wv[el * 68 + d4 * 4];
#pragma unroll
        for (int hh = 0; hh < 2; ++hh) {
            const float4 xv = *(const float4*)&xs[(h0 + hh) * 68 + d4 * 4];
            aq[hh] = fmaf(xv.x, wqv.x, fmaf(xv.y, wqv.y, fmaf(xv.z, wqv.z, fmaf(xv.w, wqv.w, aq[hh]))));
            ak[hh] = fmaf(xv.x, wkv.x, fmaf(xv.y, wkv.y, fmaf(xv.z, wkv.z, fmaf(xv.w, wkv.w, ak[hh]))));
            av[hh] = fmaf(xv.x, wvv.x, fmaf(xv.y, wvv.y, fmaf(xv.z, wvv.z, fmaf(xv.w, wvv.w, av[hh]))));
        }
    }
    const size_t off = (size_t)ns * EMB + half * 512 + 2 * tid;   // even
    *(ushort2*)&Q[off] = make_ushort2(f2bf(aq[0]), f2bf(aq[1]));
    *(ushort2*)&K[off] = make_ushort2(f2bf(ak[0]), f2bf(ak[1]));
    *(ushort2*)&V[off] = make_ushort2(f2bf(av[0]), f2bf(av[1]));
}

// ---------------------------------------------------------------------------
// Kernel 2: fused energy -> softmax(h) -> sum(t). Round-6 version (measured
// best: 40.2us). Wave tile: 2 s x half e-range (eh); lane = one uint4 (8
// bf16); h-sum = 7 local adds + 1 shfl_xor(1); reg double-buffer on K/V.
// Grid: 2n * 32st(8s) * 2eh * 16tc = 2048 blocks.
// ---------------------------------------------------------------------------
__global__ __attribute__((amdgpu_waves_per_eu(4, 8))) __launch_bounds__(256)
void attn_kernel(
    const ushortT* __restrict__ Q,
    const ushortT* __restrict__ K,
    const ushortT* __restrict__ V,
    float* __restrict__ AO)
{
    const int b    = blockIdx.x;
    const int tc   = b & 15;
    const int eh   = (b >> 4) & 1;
    const int st   = (b >> 5) & 31;
    const int n    = b >> 10;
    const int wave = threadIdx.x >> 6;
    const int l    = threadIdx.x & 63;
    const int s0   = st * 8 + wave * 2;
    const int t0   = tc * 16;

    float qa0[8], qa1[8];
    {
        const uint4* qp = (const uint4*)(Q + (size_t)(n * SQL + s0) * EMB + 512 * eh) + l;
        unpk8(qp[0], qa0);
        unpk8(qp[128], qa1);   // next s row = 1024 ushorts = 128 uint4
    }

    float a0[8], a1[8];
#pragma unroll
    for (int i = 0; i < 8; ++i) { a0[i] = 0.f; a1[i] = 0.f; }

    const uint4* kp = (const uint4*)(K + (size_t)(n * SQL + t0) * EMB + 512 * eh) + l;
    const uint4* vp = (const uint4*)(V + (size_t)(n * SQL + t0) * EMB + 512 * eh) + l;

    uint4 kk = kp[0];
    uint4 vv = vp[0];
    kp += 128; vp += 128;

    for (int tt = 0; tt < 16; ++tt) {
        uint4 kn, vn;
        if (tt < 15) {                // prefetch next t (reg double-buffer)
            kn = kp[0];
            vn = vp[0];
            kp += 128; vp += 128;
        }
        float ku[8], vu[8], p0[8], p1[8];
        unpk8(kk, ku);
#pragma unroll
        for (int i = 0; i < 8; ++i) p0[i] = fexp2(qa0[i] * ku[i]);
#pragma unroll
        for (int i = 0; i < 8; ++i) p1[i] = fexp2(qa1[i] * ku[i]);
        float u0 = ((p0[0] + p0[1]) + (p0[2] + p0[3])) + ((p0[4] + p0[5]) + (p0[6] + p0[7]));
        float u1 = ((p1[0] + p1[1]) + (p1[2] + p1[3])) + ((p1[4] + p1[5]) + (p1[6] + p1[7]));
        u0 += __shfl_xor(u0, 1);
        u1 += __shfl_xor(u1, 1);
        const float rs0 = frcp(u0);
        const float rs1 = frcp(u1);
        unpk8(vv, vu);
#pragma unroll
        for (int i = 0; i < 8; ++i) {
            a0[i] = fmaf(p0[i] * rs0, vu[i], a0[i]);
            a1[i] = fmaf(p1[i] * rs1, vu[i], a1[i]);
        }
        kk = kn; vv = vn;
    }

    // element (within row) = 512eh + 8l + c  ->  e = 32eh+(l>>1), h = 8(l&1)+c
    // AO channel = h*64 + e = 512(l&1) + 64c + 32eh + (l>>1)
    float* base0 = AO + (size_t)(n * SQL + s0) * EMB + 512 * (l & 1) + 32 * eh + (l >> 1);
    float* base1 = base0 + EMB;
#pragma unroll
    for (int c = 0; c < 8; ++c) {
        atomicAdd(base0 + 64 * c, a0[c]);
        atomicAdd(base1 + 64 * c, a1[c]);
    }
}

// ---------------------------------------------------------------------------
// Kernel 3: out += AO @ Wo^T via bf16 MFMA (16x16x32). AO (f32) is converted
// to bf16 during LDS staging. 64x64 tile, 4 waves = 2x2 quadrants of 32x32,
// k-split 4 -> f32 atomicAdd into bias-initialized out.
// Fragment map (m89-verified family): A/B lane&15 = row/col, k = 8*(lane>>4)
// + e (8 contiguous bf16 -> ds_read_b128); C: col = lane&15, row =
// (lane>>4)*4 + reg. LDS rows padded to 40 bf16 (80B) -> 2-way max (free).
// Grid = 8rt * 16jt * 4kc = 512 blocks.
// ---------------------------------------------------------------------------
__global__ __launch_bounds__(256) void proj_kernel(
    const float* __restrict__ AO,
    const float* __restrict__ Wo,
    float* __restrict__ out)
{
    __shared__ ushortT As[64 * 40];
    __shared__ ushortT Bs[64 * 40];

    const int b  = blockIdx.x;
    const int kc = b & 3;
    const int jt = (b >> 2) & 15;
    const int rt = b >> 6;
    const int tid = threadIdx.x;
    const int r0 = rt * 64, j0 = jt * 64, k0 = kc * 256;

    const int w  = tid >> 6;        // wave 0..3
    const int wr = w >> 1;          // quadrant row
    const int wc = w & 1;           // quadrant col
    const int l  = tid & 63;
    const int lr = l & 15;
    const int lk = l >> 4;

    f32x4 c00 = {0.f, 0.f, 0.f, 0.f};
    f32x4 c01 = {0.f, 0.f, 0.f, 0.f};
    f32x4 c10 = {0.f, 0.f, 0.f, 0.f};
    f32x4 c11 = {0.f, 0.f, 0.f, 0.f};

    const int srow = tid >> 3;       // staging row 0..63 (two halves)
    const int skq  = tid & 7;        // k-quad

    for (int kt = 0; kt < 8; ++kt) {
        const int kb = k0 + kt * 32;
        __syncthreads();
#pragma unroll
        for (int it = 0; it < 2; ++it) {
            const int row = it * 32 + srow;
            const float4 a = *(const float4*)&AO[(size_t)(r0 + row) * EMB + kb + skq * 4];
            ushortT* da = &As[row * 40 + skq * 4];
            da[0] = f2bf(a.x); da[1] = f2bf(a.y); da[2] = f2bf(a.z); da[3] = f2bf(a.w);
            const float4 wv = *(const float4*)&Wo[(size_t)(j0 + row) * EMB + kb + skq * 4];
            ushortT* db = &Bs[row * 40 + skq * 4];
            db[0] = f2bf(wv.x); db[1] = f2bf(wv.y); db[2] = f2bf(wv.z); db[3] = f2bf(wv.w);
        }
        __syncthreads();

        const bf16x8 a0 = *(const bf16x8*)&As[(wr * 32 + lr) * 40 + lk * 8];
        const bf16x8 a1 = *(const bf16x8*)&As[(wr * 32 + 16 + lr) * 40 + lk * 8];
        const bf16x8 b0 = *(const bf16x8*)&Bs[(wc * 32 + lr) * 40 + lk * 8];
        const bf16x8 b1 = *(const bf16x8*)&Bs[(wc * 32 + 16 + lr) * 40 + lk * 8];
        c00 = __builtin_amdgcn_mfma_f32_16x16x32_bf16(a0, b0, c00, 0, 0, 0);
        c01 = __builtin_amdgcn_mfma_f32_16x16x32_bf16(a0, b1, c01, 0, 0, 0);
        c10 = __builtin_amdgcn_mfma_f32_16x16x32_bf16(a1, b0, c10, 0, 0, 0);
        c11 = __builtin_amdgcn_mfma_f32_16x16x32_bf16(a1, b1, c11, 0, 0, 0);
    }

    // C: row = (lane>>4)*4 + e, col = lane&15 (within each 16x16 fragment)
    const int rbase = r0 + wr * 32 + lk * 4;
    const int jbase = j0 + wc * 32 + lr;
#pragma unroll
    for (int e = 0; e < 4; ++e) {
        atomicAdd(&out[(size_t)(rbase + e) * EMB + jbase],           c00[e]);
        atomicAdd(&out[(size_t)(rbase + e) * EMB + jbase + 16],      c01[e]);
        atomicAdd(&out[(size_t)(rbase + 16 + e) * EMB + jbase],      c10[e]);
        atomicAdd(&out[(size_t)(rbase + 16 + e) * EMB + jbase + 16], c11[e]);
    }
}

extern "C" void kernel_launch(void* const* d_in, const int* in_sizes, int n_in,
                              void* d_out, int out_size, void* d_ws, size_t ws_size,
                              hipStream_t stream)
{
    const float* x  = (const float*)d_in[0];
    const float* Wq = (const float*)d_in[1];
    const float* Wk = (const float*)d_in[2];
    const float* Wv = (const float*)d_in[3];
    const float* Wo = (const float*)d_in[4];
    const float* bo = (const float*)d_in[5];

    float* ws = (float*)d_ws;
    ushortT* Q = (ushortT*)ws;              // 524288 bf16 = 1 MB
    ushortT* K = (ushortT*)(ws + 262144);   // 1 MB
    ushortT* V = (ushortT*)(ws + 524288);   // 1 MB
    float* AO  = ws + 786432;               // 524288 f32 = 2 MB

    init_kernel<<<512, 256, 0, stream>>>(bo, AO, (float*)d_out);
    qkv_kernel<<<1024, 256, 0, stream>>>(x, Wq, Wk, Wv, Q, K, V);
    attn_kernel<<<2048, 256, 0, stream>>>(Q, K, V, AO);
    proj_kernel<<<512, 256, 0, stream>>>(AO, Wo, (float*)d_out);
}

// Round 10
// 63.329 us; speedup vs baseline: 1.1125x; 1.1125x over previous
//
#include <hip/hip_runtime.h>

#define NB 2
#define SQL 256
#define NH 16
#define HD 64
#define EMB 1024

typedef unsigned short ushortT;
typedef unsigned int uintT;
typedef __attribute__((ext_vector_type(8))) short bf16x8;
typedef __attribute__((ext_vector_type(4))) float f32x4;

// log2(e) / sqrt(EMBED): folded into Wq so softmax = 2^(q*k)
__device__ __constant__ float kQSCALE = 1.4426950408889634f / 32.0f;

__device__ __forceinline__ float fexp2(float x) { return __builtin_amdgcn_exp2f(x); }
__device__ __forceinline__ float frcp(float x)  { return __builtin_amdgcn_rcpf(x); }

__device__ __forceinline__ ushortT f2bf(float x) {
    uintT u = __float_as_uint(x);
    u += 0x7fffu + ((u >> 16) & 1u);        // RNE
    return (ushortT)(u >> 16);
}
__device__ __forceinline__ ushort4 f2bf4(float4 a) {
    return make_ushort4(f2bf(a.x), f2bf(a.y), f2bf(a.z), f2bf(a.w));
}
// unpack 8 bf16 (element order = memory order) to f32
__device__ __forceinline__ void unpk8(uint4 u, float* f) {
    f[0] = __uint_as_float(u.x << 16); f[1] = __uint_as_float(u.x & 0xffff0000u);
    f[2] = __uint_as_float(u.y << 16); f[3] = __uint_as_float(u.y & 0xffff0000u);
    f[4] = __uint_as_float(u.z << 16); f[5] = __uint_as_float(u.z & 0xffff0000u);
    f[6] = __uint_as_float(u.w << 16); f[7] = __uint_as_float(u.w & 0xffff0000u);
}

// ---------------------------------------------------------------------------
// Kernel 1: q/k/v projections via bf16 MFMA (16x16x32). Block = 2 (n,s) rows.
// M = 16 h of one (n,s); N = 64 e (4 frags); K = 64 d (2 steps).
// A[h,d] = x[ns][h*64+d] (bf16 in LDS, pad 72); B[d,e-col] = W[e][d].
// C: col = lane&15 = e, row = (lane>>4)*4+reg = h  ->  ushort4 write at
// [ns][e*16 + h]. Also folds: AO=0, out=bias init, Wo -> bf16 (Wob).
// Grid 256 blocks x 256 threads.
// ---------------------------------------------------------------------------
__global__ __launch_bounds__(256) void qkv_kernel(
    const float* __restrict__ x,
    const float* __restrict__ Wq,
    const float* __restrict__ Wk,
    const float* __restrict__ Wv,
    const float* __restrict__ Wo,
    const float* __restrict__ bo,
    ushortT* __restrict__ Q,
    ushortT* __restrict__ K,
    ushortT* __restrict__ V,
    float* __restrict__ AO,
    float* __restrict__ out,
    ushortT* __restrict__ Wob)
{
    __shared__ ushortT wls[3][64 * 72];
    __shared__ ushortT xs[2][16 * 72];

    const int tid = threadIdx.x;
    const int ns0 = blockIdx.x * 2;
    const int g   = blockIdx.x * 256 + tid;   // 65536 threads total

    // --- fold: init AO = 0, out = bias (2 float4 each per thread) ---
    {
        const float4 z = make_float4(0.f, 0.f, 0.f, 0.f);
        ((float4*)AO)[g] = z;
        ((float4*)AO)[g + 65536] = z;
        const float4 bb = ((const float4*)bo)[g & 255];   // 65536 % 256 == 0
        ((float4*)out)[g] = bb;
        ((float4*)out)[g + 65536] = bb;
    }
    // --- fold: Wo -> bf16 (1M floats, 4 float4/thread) ---
#pragma unroll
    for (int j = 0; j < 4; ++j) {
        const int f4 = j * 65536 + g;
        ((ushort4*)Wob)[f4] = f2bf4(((const float4*)Wo)[f4]);
    }

    // --- stage weights (bf16, rows padded to 72) ---
#pragma unroll
    for (int m = 0; m < 3; ++m) {
        const float4* src = (m == 0) ? (const float4*)Wq
                          : (m == 1) ? (const float4*)Wk : (const float4*)Wv;
#pragma unroll
        for (int j = 0; j < 4; ++j) {
            const int idx = j * 256 + tid;     // 1024 float4
            const int e   = idx >> 4;
            const int d4  = idx & 15;
            float4 a = src[idx];
            if (m == 0) { a.x *= kQSCALE; a.y *= kQSCALE; a.z *= kQSCALE; a.w *= kQSCALE; }
            *(ushort4*)&wls[m][e * 72 + d4 * 4] = f2bf4(a);
        }
    }
    // --- stage 2 x rows (bf16) ---
#pragma unroll
    for (int j = 0; j < 2; ++j) {
        const int idx = j * 256 + tid;         // 512 float4 = 2 rows
        const int r   = idx >> 8;
        const int h   = (idx >> 4) & 15;
        const int d4  = idx & 15;
        const float4 a = ((const float4*)(x + (size_t)(ns0 + r) * EMB))[idx & 255];
        *(ushort4*)&xs[r][h * 72 + d4 * 4] = f2bf4(a);
    }
    __syncthreads();

    // --- compute: wave w -> ns-row (w>>1), e-half (w&1) ---
    const int w   = tid >> 6;
    const int nsr = w >> 1;
    const int eb0 = (w & 1) * 32;
    const int l   = tid & 63;
    const int lr  = l & 15;
    const int lk  = l >> 4;

    const bf16x8 a0 = *(const bf16x8*)&xs[nsr][lr * 72 + lk * 8];
    const bf16x8 a1 = *(const bf16x8*)&xs[nsr][lr * 72 + 32 + lk * 8];

#pragma unroll
    for (int m = 0; m < 3; ++m) {
        ushortT* outp = (m == 0) ? Q : (m == 1) ? K : V;
#pragma unroll
        for (int ef = 0; ef < 2; ++ef) {
            const int eb = eb0 + ef * 16;
            const bf16x8 b0 = *(const bf16x8*)&wls[m][(eb + lr) * 72 + lk * 8];
            const bf16x8 b1 = *(const bf16x8*)&wls[m][(eb + lr) * 72 + 32 + lk * 8];
            f32x4 c = {0.f, 0.f, 0.f, 0.f};
            c = __builtin_amdgcn_mfma_f32_16x16x32_bf16(a0, b0, c, 0, 0, 0);
            c = __builtin_amdgcn_mfma_f32_16x16x32_bf16(a1, b1, c, 0, 0, 0);
            // e = eb + lr, h = lk*4 + reg -> [ns][e*16+h], 4 consecutive h
            ushortT* dst = outp + (size_t)(ns0 + nsr) * EMB + (eb + lr) * 16 + lk * 4;
            *(ushort4*)dst = make_ushort4(f2bf(c[0]), f2bf(c[1]), f2bf(c[2]), f2bf(c[3]));
        }
    }
}

// ---------------------------------------------------------------------------
// Kernel 2: fused energy -> softmax(h) -> sum(t). Round-6 math/tile (best
// measured), loop rewritten as unconditional ping-pong unroll-2: no per-iter
// branch/exec-mask, fixed-offset loads, one pointer bump per 2 iters. The
// final iteration's prefetch over-reads into the adjacent ws buffer (safe).
// Grid: 2n * 32st(8s) * 2eh * 16tc = 2048 blocks.
// ---------------------------------------------------------------------------
#define ATTN_STEP(KU4, VU4)                                                    \
    {                                                                          \
        float ku[8], vu[8], p0[8], p1[8];                                      \
        unpk8(KU4, ku);                                                        \
        _Pragma("unroll")                                                      \
        for (int i = 0; i < 8; ++i) p0[i] = fexp2(qa0[i] * ku[i]);             \
        _Pragma("unroll")                                                      \
        for (int i = 0; i < 8; ++i) p1[i] = fexp2(qa1[i] * ku[i]);             \
        float u0 = ((p0[0]+p0[1]) + (p0[2]+p0[3])) + ((p0[4]+p0[5]) + (p0[6]+p0[7])); \
        float u1 = ((p1[0]+p1[1]) + (p1[2]+p1[3])) + ((p1[4]+p1[5]) + (p1[6]+p1[7])); \
        u0 += __shfl_xor(u0, 1);                                               \
        u1 += __shfl_xor(u1, 1);                                               \
        const float rs0 = frcp(u0);                                            \
        const float rs1 = frcp(u1);                                            \
        unpk8(VU4, vu);                                                        \
        _Pragma("unroll")                                                      \
        for (int i = 0; i < 8; ++i) {                                          \
            a0[i] = fmaf(p0[i] * rs0, vu[i], a0[i]);                           \
            a1[i] = fmaf(p1[i] * rs1, vu[i], a1[i]);                           \
        }                                                                      \
    }

__global__ __attribute__((amdgpu_waves_per_eu(4, 8))) __launch_bounds__(256)
void attn_kernel(
    const ushortT* __restrict__ Q,
    const ushortT* __restrict__ K,
    const ushortT* __restrict__ V,
    float* __restrict__ AO)
{
    const int b    = blockIdx.x;
    const int tc   = b & 15;
    const int eh   = (b >> 4) & 1;
    const int st   = (b >> 5) & 31;
    const int n    = b >> 10;
    const int wave = threadIdx.x >> 6;
    const int l    = threadIdx.x & 63;
    const int s0   = st * 8 + wave * 2;
    const int t0   = tc * 16;

    float qa0[8], qa1[8];
    {
        const uint4* qp = (const uint4*)(Q + (size_t)(n * SQL + s0) * EMB + 512 * eh) + l;
        unpk8(qp[0], qa0);
        unpk8(qp[128], qa1);   // next s row = 1024 ushorts = 128 uint4
    }

    float a0[8], a1[8];
#pragma unroll
    for (int i = 0; i < 8; ++i) { a0[i] = 0.f; a1[i] = 0.f; }

    const uint4* kp = (const uint4*)(K + (size_t)(n * SQL + t0) * EMB + 512 * eh) + l;
    const uint4* vp = (const uint4*)(V + (size_t)(n * SQL + t0) * EMB + 512 * eh) + l;

    uint4 ka = kp[0];
    uint4 va = vp[0];

#pragma unroll
    for (int tt = 0; tt < 16; tt += 2) {
        const uint4 kb = kp[128], vb = vp[128];   // t+1
        ATTN_STEP(ka, va);
        ka = kp[256]; va = vp[256];               // t+2 (tail over-read: safe)
        kp += 256; vp += 256;
        ATTN_STEP(kb, vb);
    }

    // element (within row) = 512eh + 8l + c  ->  e = 32eh+(l>>1), h = 8(l&1)+c
    // AO channel = h*64 + e = 512(l&1) + 64c + 32eh + (l>>1)
    float* base0 = AO + (size_t)(n * SQL + s0) * EMB + 512 * (l & 1) + 32 * eh + (l >> 1);
    float* base1 = base0 + EMB;
#pragma unroll
    for (int c = 0; c < 8; ++c) {
        atomicAdd(base0 + 64 * c, a0[c]);
        atomicAdd(base1 + 64 * c, a1[c]);
    }
}

// ---------------------------------------------------------------------------
// Kernel 3: out += AO @ Wob^T via bf16 MFMA (16x16x32). AO converted to bf16
// during LDS staging (ushort4 vector writes); Wob pre-converted by qkv so B
// staging is a straight uint4 copy. 64x64 tile, 4 waves = 2x2 quadrants,
// k-split 4 -> f32 atomicAdd into bias-initialized out. LDS rows padded to
// 40 ushorts. Grid = 8rt * 16jt * 4kc = 512 blocks.
// ---------------------------------------------------------------------------
__global__ __launch_bounds__(256) void proj_kernel(
    const float* __restrict__ AO,
    const ushortT* __restrict__ Wob,
    float* __restrict__ out)
{
    __shared__ ushortT As[64 * 40];
    __shared__ ushortT Bs[64 * 40];

    const int b  = blockIdx.x;
    const int kc = b & 3;
    const int jt = (b >> 2) & 15;
    const int rt = b >> 6;
    const int tid = threadIdx.x;
    const int r0 = rt * 64, j0 = jt * 64, k0 = kc * 256;

    const int w  = tid >> 6;
    const int wr = w >> 1;
    const int wc = w & 1;
    const int l  = tid & 63;
    const int lr = l & 15;
    const int lk = l >> 4;

    f32x4 c00 = {0.f, 0.f, 0.f, 0.f};
    f32x4 c01 = {0.f, 0.f, 0.f, 0.f};
    f32x4 c10 = {0.f, 0.f, 0.f, 0.f};
    f32x4 c11 = {0.f, 0.f, 0.f, 0.f};

    for (int kt = 0; kt < 8; ++kt) {
        const int kb = k0 + kt * 32;
        __syncthreads();
        // A: 64 rows x 32 k f32 -> bf16 (2 float4 + 8 f2bf + 2 ushort4/thread)
#pragma unroll
        for (int it = 0; it < 2; ++it) {
            const int f   = it * 256 + tid;
            const int row = f >> 3;
            const int kq  = f & 7;
            const float4 a = *(const float4*)&AO[(size_t)(r0 + row) * EMB + kb + kq * 4];
            *(ushort4*)&As[row * 40 + kq * 4] = f2bf4(a);
        }
        // B: 64 rows x 32 k bf16 -> straight uint4 copy (1/thread)
        {
            const int row = tid >> 2;
            const int ko  = tid & 3;
            const uint4 wv = *(const uint4*)&Wob[(size_t)(j0 + row) * EMB + kb + ko * 8];
            *(uint4*)&Bs[row * 40 + ko * 8] = wv;
        }
        __syncthreads();

        const bf16x8 a0 = *(const bf16x8*)&As[(wr * 32 + lr) * 40 + lk * 8];
        const bf16x8 a1 = *(const bf16x8*)&As[(wr * 32 + 16 + lr) * 40 + lk * 8];
        const bf16x8 b0 = *(const bf16x8*)&Bs[(wc * 32 + lr) * 40 + lk * 8];
        const bf16x8 b1 = *(const bf16x8*)&Bs[(wc * 32 + 16 + lr) * 40 + lk * 8];
        c00 = __builtin_amdgcn_mfma_f32_16x16x32_bf16(a0, b0, c00, 0, 0, 0);
        c01 = __builtin_amdgcn_mfma_f32_16x16x32_bf16(a0, b1, c01, 0, 0, 0);
        c10 = __builtin_amdgcn_mfma_f32_16x16x32_bf16(a1, b0, c10, 0, 0, 0);
        c11 = __builtin_amdgcn_mfma_f32_16x16x32_bf16(a1, b1, c11, 0, 0, 0);
    }

    const int rbase = r0 + wr * 32 + lk * 4;
    const int jbase = j0 + wc * 32 + lr;
#pragma unroll
    for (int e = 0; e < 4; ++e) {
        atomicAdd(&out[(size_t)(rbase + e) * EMB + jbase],           c00[e]);
        atomicAdd(&out[(size_t)(rbase + e) * EMB + jbase + 16],      c01[e]);
        atomicAdd(&out[(size_t)(rbase + 16 + e) * EMB + jbase],      c10[e]);
        atomicAdd(&out[(size_t)(rbase + 16 + e) * EMB + jbase + 16], c11[e]);
    }
}

extern "C" void kernel_launch(void* const* d_in, const int* in_sizes, int n_in,
                              void* d_out, int out_size, void* d_ws, size_t ws_size,
                              hipStream_t stream)
{
    const float* x  = (const float*)d_in[0];
    const float* Wq = (const float*)d_in[1];
    const float* Wk = (const float*)d_in[2];
    const float* Wv = (const float*)d_in[3];
    const float* Wo = (const float*)d_in[4];
    const float* bo = (const float*)d_in[5];

    float* ws = (float*)d_ws;
    ushortT* Q   = (ushortT*)ws;              // 524288 bf16 = 1 MB
    ushortT* K   = (ushortT*)(ws + 262144);   // 1 MB
    ushortT* V   = (ushortT*)(ws + 524288);   // 1 MB
    float*   AO  = ws + 786432;               // 524288 f32 = 2 MB
    ushortT* Wob = (ushortT*)(ws + 1310720);  // 1048576 bf16 = 2 MB

    qkv_kernel<<<256, 256, 0, stream>>>(x, Wq, Wk, Wv, Wo, bo, Q, K, V, AO,
                                        (float*)d_out, Wob);
    attn_kernel<<<2048, 256, 0, stream>>>(Q, K, V, AO);
    proj_kernel<<<512, 256, 0, stream>>>(AO, Wob, (float*)d_out);
}

// Round 11
// 59.701 us; speedup vs baseline: 1.1801x; 1.0608x over previous
//
#include <hip/hip_runtime.h>

#define NB 2
#define SQL 256
#define NH 16
#define HD 64
#define EMB 1024

typedef unsigned short ushortT;
typedef unsigned int uintT;
typedef __attribute__((ext_vector_type(8))) short bf16x8;
typedef __attribute__((ext_vector_type(4))) float f32x4;

// log2(e) / sqrt(EMBED): folded into Wq so softmax = 2^(q*k)
__device__ __constant__ float kQSCALE = 1.4426950408889634f / 32.0f;

__device__ __forceinline__ float fexp2(float x) { return __builtin_amdgcn_exp2f(x); }
__device__ __forceinline__ float frcp(float x)  { return __builtin_amdgcn_rcpf(x); }

__device__ __forceinline__ ushortT f2bf(float x) {
    uintT u = __float_as_uint(x);
    u += 0x7fffu + ((u >> 16) & 1u);        // RNE
    return (ushortT)(u >> 16);
}
__device__ __forceinline__ ushort4 f2bf4(float4 a) {
    return make_ushort4(f2bf(a.x), f2bf(a.y), f2bf(a.z), f2bf(a.w));
}
// unpack 8 bf16 (element order = memory order) to f32
__device__ __forceinline__ void unpk8(uint4 u, float* f) {
    f[0] = __uint_as_float(u.x << 16); f[1] = __uint_as_float(u.x & 0xffff0000u);
    f[2] = __uint_as_float(u.y << 16); f[3] = __uint_as_float(u.y & 0xffff0000u);
    f[4] = __uint_as_float(u.z << 16); f[5] = __uint_as_float(u.z & 0xffff0000u);
    f[6] = __uint_as_float(u.w << 16); f[7] = __uint_as_float(u.w & 0xffff0000u);
}
// pair-sum via DPP quad_perm [1,0,3,2]: lane(2i) <-> lane(2i+1). VALU pipe,
// replaces ds_swizzle (__shfl_xor) in the softmax critical path.
__device__ __forceinline__ float pairsum_dpp(float u) {
    const int j = __builtin_amdgcn_mov_dpp(__float_as_int(u), 0xB1, 0xF, 0xF, true);
    return u + __int_as_float(j);
}

// ---------------------------------------------------------------------------
// Kernel 1: q/k/v projections via bf16 MFMA (16x16x32). Block = 2 (n,s) rows.
// Folds: AO=0, out=bias init, Wo -> bf16 (Wob). Grid 256 x 256.
// ---------------------------------------------------------------------------
__global__ __launch_bounds__(256) void qkv_kernel(
    const float* __restrict__ x,
    const float* __restrict__ Wq,
    const float* __restrict__ Wk,
    const float* __restrict__ Wv,
    const float* __restrict__ Wo,
    const float* __restrict__ bo,
    ushortT* __restrict__ Q,
    ushortT* __restrict__ K,
    ushortT* __restrict__ V,
    float* __restrict__ AO,
    float* __restrict__ out,
    ushortT* __restrict__ Wob)
{
    __shared__ ushortT wls[3][64 * 72];
    __shared__ ushortT xs[2][16 * 72];

    const int tid = threadIdx.x;
    const int ns0 = blockIdx.x * 2;
    const int g   = blockIdx.x * 256 + tid;   // 65536 threads total

    {
        const float4 z = make_float4(0.f, 0.f, 0.f, 0.f);
        ((float4*)AO)[g] = z;
        ((float4*)AO)[g + 65536] = z;
        const float4 bb = ((const float4*)bo)[g & 255];
        ((float4*)out)[g] = bb;
        ((float4*)out)[g + 65536] = bb;
    }
#pragma unroll
    for (int j = 0; j < 4; ++j) {
        const int f4 = j * 65536 + g;
        ((ushort4*)Wob)[f4] = f2bf4(((const float4*)Wo)[f4]);
    }

#pragma unroll
    for (int m = 0; m < 3; ++m) {
        const float4* src = (m == 0) ? (const float4*)Wq
                          : (m == 1) ? (const float4*)Wk : (const float4*)Wv;
#pragma unroll
        for (int j = 0; j < 4; ++j) {
            const int idx = j * 256 + tid;
            const int e   = idx >> 4;
            const int d4  = idx & 15;
            float4 a = src[idx];
            if (m == 0) { a.x *= kQSCALE; a.y *= kQSCALE; a.z *= kQSCALE; a.w *= kQSCALE; }
            *(ushort4*)&wls[m][e * 72 + d4 * 4] = f2bf4(a);
        }
    }
#pragma unroll
    for (int j = 0; j < 2; ++j) {
        const int idx = j * 256 + tid;
        const int r   = idx >> 8;
        const int h   = (idx >> 4) & 15;
        const int d4  = idx & 15;
        const float4 a = ((const float4*)(x + (size_t)(ns0 + r) * EMB))[idx & 255];
        *(ushort4*)&xs[r][h * 72 + d4 * 4] = f2bf4(a);
    }
    __syncthreads();

    const int w   = tid >> 6;
    const int nsr = w >> 1;
    const int eb0 = (w & 1) * 32;
    const int l   = tid & 63;
    const int lr  = l & 15;
    const int lk  = l >> 4;

    const bf16x8 a0 = *(const bf16x8*)&xs[nsr][lr * 72 + lk * 8];
    const bf16x8 a1 = *(const bf16x8*)&xs[nsr][lr * 72 + 32 + lk * 8];

#pragma unroll
    for (int m = 0; m < 3; ++m) {
        ushortT* outp = (m == 0) ? Q : (m == 1) ? K : V;
#pragma unroll
        for (int ef = 0; ef < 2; ++ef) {
            const int eb = eb0 + ef * 16;
            const bf16x8 b0 = *(const bf16x8*)&wls[m][(eb + lr) * 72 + lk * 8];
            const bf16x8 b1 = *(const bf16x8*)&wls[m][(eb + lr) * 72 + 32 + lk * 8];
            f32x4 c = {0.f, 0.f, 0.f, 0.f};
            c = __builtin_amdgcn_mfma_f32_16x16x32_bf16(a0, b0, c, 0, 0, 0);
            c = __builtin_amdgcn_mfma_f32_16x16x32_bf16(a1, b1, c, 0, 0, 0);
            ushortT* dst = outp + (size_t)(ns0 + nsr) * EMB + (eb + lr) * 16 + lk * 4;
            *(ushort4*)dst = make_ushort4(f2bf(c[0]), f2bf(c[1]), f2bf(c[2]), f2bf(c[3]));
        }
    }
}

// ---------------------------------------------------------------------------
// Kernel 2: fused energy -> softmax(h) -> sum(t). Round-9 math/tile, with:
// (a) pair-sum via DPP (no DS-pipe in the softmax chain), (b) K prefetched
// 2 iterations ahead (exp input, ~380cy load-to-use > L2 latency), V 1 iter
// ahead (used late). Tail over-reads land in adjacent ws buffers (safe).
// Grid: 2n * 32st(8s) * 2eh * 16tc = 2048 blocks.
// ---------------------------------------------------------------------------
#define ATTN_STEP(KU4, VU4)                                                    \
    {                                                                          \
        float ku[8], vu[8], p0[8], p1[8];                                      \
        unpk8(KU4, ku);                                                        \
        _Pragma("unroll")                                                      \
        for (int i = 0; i < 8; ++i) p0[i] = fexp2(qa0[i] * ku[i]);             \
        _Pragma("unroll")                                                      \
        for (int i = 0; i < 8; ++i) p1[i] = fexp2(qa1[i] * ku[i]);             \
        float u0 = ((p0[0]+p0[1]) + (p0[2]+p0[3])) + ((p0[4]+p0[5]) + (p0[6]+p0[7])); \
        float u1 = ((p1[0]+p1[1]) + (p1[2]+p1[3])) + ((p1[4]+p1[5]) + (p1[6]+p1[7])); \
        const float rs0 = frcp(pairsum_dpp(u0));                               \
        const float rs1 = frcp(pairsum_dpp(u1));                               \
        unpk8(VU4, vu);                                                        \
        _Pragma("unroll")                                                      \
        for (int i = 0; i < 8; ++i) {                                          \
            a0[i] = fmaf(p0[i] * rs0, vu[i], a0[i]);                           \
            a1[i] = fmaf(p1[i] * rs1, vu[i], a1[i]);                           \
        }                                                                      \
    }

__global__ __launch_bounds__(256) void attn_kernel(
    const ushortT* __restrict__ Q,
    const ushortT* __restrict__ K,
    const ushortT* __restrict__ V,
    float* __restrict__ AO)
{
    const int b    = blockIdx.x;
    const int tc   = b & 15;
    const int eh   = (b >> 4) & 1;
    const int st   = (b >> 5) & 31;
    const int n    = b >> 10;
    const int wave = threadIdx.x >> 6;
    const int l    = threadIdx.x & 63;
    const int s0   = st * 8 + wave * 2;
    const int t0   = tc * 16;

    float qa0[8], qa1[8];
    {
        const uint4* qp = (const uint4*)(Q + (size_t)(n * SQL + s0) * EMB + 512 * eh) + l;
        unpk8(qp[0], qa0);
        unpk8(qp[128], qa1);
    }

    float a0[8], a1[8];
#pragma unroll
    for (int i = 0; i < 8; ++i) { a0[i] = 0.f; a1[i] = 0.f; }

    const uint4* kp = (const uint4*)(K + (size_t)(n * SQL + t0) * EMB + 512 * eh) + l;
    const uint4* vp = (const uint4*)(V + (size_t)(n * SQL + t0) * EMB + 512 * eh) + l;

    uint4 ka = kp[0];      // k(t)
    uint4 kb = kp[128];    // k(t+1)
    uint4 va = vp[0];      // v(t)

#pragma unroll
    for (int tt = 0; tt < 16; tt += 2) {
        const uint4 kn2 = kp[256];   // k(t+2)
        const uint4 vb  = vp[128];   // v(t+1)
        ATTN_STEP(ka, va);           // consume t
        const uint4 kn3 = kp[384];   // k(t+3) (tail over-read: safe)
        va = vp[256];                // v(t+2) (tail over-read: safe)
        kp += 256; vp += 256;
        ATTN_STEP(kb, vb);           // consume t+1
        ka = kn2; kb = kn3;
    }

    // element = 512eh + 8l + c  ->  e = 32eh+(l>>1), h = 8(l&1)+c
    // AO channel = h*64 + e = 512(l&1) + 64c + 32eh + (l>>1)
    float* base0 = AO + (size_t)(n * SQL + s0) * EMB + 512 * (l & 1) + 32 * eh + (l >> 1);
    float* base1 = base0 + EMB;
#pragma unroll
    for (int c = 0; c < 8; ++c) {
        atomicAdd(base0 + 64 * c, a0[c]);
        atomicAdd(base1 + 64 * c, a1[c]);
    }
}

// ---------------------------------------------------------------------------
// Kernel 3: out += AO @ Wob^T via bf16 MFMA. 64r x 128j tile, 512 threads
// (8 waves = 2x4 grid of 32x32 quadrants), k-split 4 -> f32 atomicAdd into
// bias-initialized out. Halves A re-reads vs 64x64, 2x MFMA per sync.
// Grid = 8rt * 8jt * 4kc = 256 blocks.
// ---------------------------------------------------------------------------
__global__ __launch_bounds__(512) void proj_kernel(
    const float* __restrict__ AO,
    const ushortT* __restrict__ Wob,
    float* __restrict__ out)
{
    __shared__ ushortT As[64 * 40];
    __shared__ ushortT Bs[128 * 40];

    const int b  = blockIdx.x;
    const int kc = b & 3;
    const int jt = (b >> 2) & 7;
    const int rt = b >> 5;
    const int tid = threadIdx.x;
    const int r0 = rt * 64, j0 = jt * 128, k0 = kc * 256;

    const int w  = tid >> 6;        // 0..7
    const int wr = w >> 2;          // 0..1
    const int wc = w & 3;           // 0..3
    const int l  = tid & 63;
    const int lr = l & 15;
    const int lk = l >> 4;

    f32x4 c00 = {0.f, 0.f, 0.f, 0.f};
    f32x4 c01 = {0.f, 0.f, 0.f, 0.f};
    f32x4 c10 = {0.f, 0.f, 0.f, 0.f};
    f32x4 c11 = {0.f, 0.f, 0.f, 0.f};

    for (int kt = 0; kt < 8; ++kt) {
        const int kb = k0 + kt * 32;
        __syncthreads();
        // A: 64 rows x 32 k, f32 -> bf16 (512 float4, 1/thread)
        {
            const int row = tid >> 3;
            const int kq  = tid & 7;
            const float4 a = *(const float4*)&AO[(size_t)(r0 + row) * EMB + kb + kq * 4];
            *(ushort4*)&As[row * 40 + kq * 4] = f2bf4(a);
        }
        // B: 128 rows x 32 k bf16 (512 uint4, 1/thread)
        {
            const int row = tid >> 2;
            const int ko  = tid & 3;
            const uint4 wv = *(const uint4*)&Wob[(size_t)(j0 + row) * EMB + kb + ko * 8];
            *(uint4*)&Bs[row * 40 + ko * 8] = wv;
        }
        __syncthreads();

        const bf16x8 a0 = *(const bf16x8*)&As[(wr * 32 + lr) * 40 + lk * 8];
        const bf16x8 a1 = *(const bf16x8*)&As[(wr * 32 + 16 + lr) * 40 + lk * 8];
        const bf16x8 b0 = *(const bf16x8*)&Bs[(wc * 32 + lr) * 40 + lk * 8];
        const bf16x8 b1 = *(const bf16x8*)&Bs[(wc * 32 + 16 + lr) * 40 + lk * 8];
        c00 = __builtin_amdgcn_mfma_f32_16x16x32_bf16(a0, b0, c00, 0, 0, 0);
        c01 = __builtin_amdgcn_mfma_f32_16x16x32_bf16(a0, b1, c01, 0, 0, 0);
        c10 = __builtin_amdgcn_mfma_f32_16x16x32_bf16(a1, b0, c10, 0, 0, 0);
        c11 = __builtin_amdgcn_mfma_f32_16x16x32_bf16(a1, b1, c11, 0, 0, 0);
    }

    const int rbase = r0 + wr * 32 + lk * 4;
    const int jbase = j0 + wc * 32 + lr;
#pragma unroll
    for (int e = 0; e < 4; ++e) {
        atomicAdd(&out[(size_t)(rbase + e) * EMB + jbase],           c00[e]);
        atomicAdd(&out[(size_t)(rbase + e) * EMB + jbase + 16],      c01[e]);
        atomicAdd(&out[(size_t)(rbase + 16 + e) * EMB + jbase],      c10[e]);
        atomicAdd(&out[(size_t)(rbase + 16 + e) * EMB + jbase + 16], c11[e]);
    }
}

extern "C" void kernel_launch(void* const* d_in, const int* in_sizes, int n_in,
                              void* d_out, int out_size, void* d_ws, size_t ws_size,
                              hipStream_t stream)
{
    const float* x  = (const float*)d_in[0];
    const float* Wq = (const float*)d_in[1];
    const float* Wk = (const float*)d_in[2];
    const float* Wv = (const float*)d_in[3];
    const float* Wo = (const float*)d_in[4];
    const float* bo = (const float*)d_in[5];

    float* ws = (float*)d_ws;
    ushortT* Q   = (ushortT*)ws;              // 524288 bf16 = 1 MB
    ushortT* K   = (ushortT*)(ws + 262144);   // 1 MB
    ushortT* V   = (ushortT*)(ws + 524288);   // 1 MB
    float*   AO  = ws + 786432;               // 524288 f32 = 2 MB
    ushortT* Wob = (ushortT*)(ws + 1310720);  // 1048576 bf16 = 2 MB

    qkv_kernel<<<256, 256, 0, stream>>>(x, Wq, Wk, Wv, Wo, bo, Q, K, V, AO,
                                        (float*)d_out, Wob);
    attn_kernel<<<2048, 256, 0, stream>>>(Q, K, V, AO);
    proj_kernel<<<256, 512, 0, stream>>>(AO, Wob, (float*)d_out);
}

// Round 14
// 58.765 us; speedup vs baseline: 1.1989x; 1.0159x over previous
//
#include <hip/hip_runtime.h>

#define NB 2
#define SQL 256
#define NH 16
#define HD 64
#define EMB 1024

typedef unsigned short ushortT;
typedef unsigned int uintT;
typedef __attribute__((ext_vector_type(8))) short bf16x8;
typedef __attribute__((ext_vector_type(4))) float f32x4;
typedef __attribute__((ext_vector_type(2))) float f32x2;

// log2(e) / sqrt(EMBED): folded into Wq so softmax = 2^(q*k)
__device__ __constant__ float kQSCALE = 1.4426950408889634f / 32.0f;

__device__ __forceinline__ float fexp2(float x) { return __builtin_amdgcn_exp2f(x); }
__device__ __forceinline__ float frcp(float x)  { return __builtin_amdgcn_rcpf(x); }

__device__ __forceinline__ ushortT f2bf(float x) {
    uintT u = __float_as_uint(x);
    u += 0x7fffu + ((u >> 16) & 1u);        // RNE
    return (ushortT)(u >> 16);
}
__device__ __forceinline__ ushort4 f2bf4(float4 a) {
    return make_ushort4(f2bf(a.x), f2bf(a.y), f2bf(a.z), f2bf(a.w));
}
// unpack one uint32 = 2 bf16 (lo = even channel, hi = odd channel) -> f32x2
__device__ __forceinline__ f32x2 unpk2(uintT u) {
    f32x2 r;
    r.x = __uint_as_float(u << 16);
    r.y = __uint_as_float(u & 0xffff0000u);
    return r;
}
// pair-sum via DPP quad_perm [1,0,3,2]: lane(2i) <-> lane(2i+1). VALU pipe.
__device__ __forceinline__ float pairsum_dpp(float u) {
    const int j = __builtin_amdgcn_mov_dpp(__float_as_int(u), 0xB1, 0xF, 0xF, true);
    return u + __int_as_float(j);
}

// ---------------------------------------------------------------------------
// Kernel 1: q/k/v projections via bf16 MFMA (16x16x32). Block = 2 (n,s) rows.
// Folds: AO=0, out=bias init, Wo -> bf16 (Wob). Grid 256 x 256.
// ---------------------------------------------------------------------------
__global__ __launch_bounds__(256) void qkv_kernel(
    const float* __restrict__ x,
    const float* __restrict__ Wq,
    const float* __restrict__ Wk,
    const float* __restrict__ Wv,
    const float* __restrict__ Wo,
    const float* __restrict__ bo,
    ushortT* __restrict__ Q,
    ushortT* __restrict__ K,
    ushortT* __restrict__ V,
    float* __restrict__ AO,
    float* __restrict__ out,
    ushortT* __restrict__ Wob)
{
    __shared__ ushortT wls[3][64 * 72];
    __shared__ ushortT xs[2][16 * 72];

    const int tid = threadIdx.x;
    const int ns0 = blockIdx.x * 2;
    const int g   = blockIdx.x * 256 + tid;   // 65536 threads total

    {
        const float4 z = make_float4(0.f, 0.f, 0.f, 0.f);
        ((float4*)AO)[g] = z;
        ((float4*)AO)[g + 65536] = z;
        const float4 bb = ((const float4*)bo)[g & 255];
        ((float4*)out)[g] = bb;
        ((float4*)out)[g + 65536] = bb;
    }
#pragma unroll
    for (int j = 0; j < 4; ++j) {
        const int f4 = j * 65536 + g;
        ((ushort4*)Wob)[f4] = f2bf4(((const float4*)Wo)[f4]);
    }

#pragma unroll
    for (int m = 0; m < 3; ++m) {
        const float4* src = (m == 0) ? (const float4*)Wq
                          : (m == 1) ? (const float4*)Wk : (const float4*)Wv;
#pragma unroll
        for (int j = 0; j < 4; ++j) {
            const int idx = j * 256 + tid;
            const int e   = idx >> 4;
            const int d4  = idx & 15;
            float4 a = src[idx];
            if (m == 0) { a.x *= kQSCALE; a.y *= kQSCALE; a.z *= kQSCALE; a.w *= kQSCALE; }
            *(ushort4*)&wls[m][e * 72 + d4 * 4] = f2bf4(a);
        }
    }
#pragma unroll
    for (int j = 0; j < 2; ++j) {
        const int idx = j * 256 + tid;
        const int r   = idx >> 8;
        const int h   = (idx >> 4) & 15;
        const int d4  = idx & 15;
        const float4 a = ((const float4*)(x + (size_t)(ns0 + r) * EMB))[idx & 255];
        *(ushort4*)&xs[r][h * 72 + d4 * 4] = f2bf4(a);
    }
    __syncthreads();

    const int w   = tid >> 6;
    const int nsr = w >> 1;
    const int eb0 = (w & 1) * 32;
    const int l   = tid & 63;
    const int lr  = l & 15;
    const int lk  = l >> 4;

    const bf16x8 a0 = *(const bf16x8*)&xs[nsr][lr * 72 + lk * 8];
    const bf16x8 a1 = *(const bf16x8*)&xs[nsr][lr * 72 + 32 + lk * 8];

#pragma unroll
    for (int m = 0; m < 3; ++m) {
        ushortT* outp = (m == 0) ? Q : (m == 1) ? K : V;
#pragma unroll
        for (int ef = 0; ef < 2; ++ef) {
            const int eb = eb0 + ef * 16;
            const bf16x8 b0 = *(const bf16x8*)&wls[m][(eb + lr) * 72 + lk * 8];
            const bf16x8 b1 = *(const bf16x8*)&wls[m][(eb + lr) * 72 + 32 + lk * 8];
            f32x4 c = {0.f, 0.f, 0.f, 0.f};
            c = __builtin_amdgcn_mfma_f32_16x16x32_bf16(a0, b0, c, 0, 0, 0);
            c = __builtin_amdgcn_mfma_f32_16x16x32_bf16(a1, b1, c, 0, 0, 0);
            ushortT* dst = outp + (size_t)(ns0 + nsr) * EMB + (eb + lr) * 16 + lk * 4;
            *(ushort4*)dst = make_ushort4(f2bf(c[0]), f2bf(c[1]), f2bf(c[2]), f2bf(c[3]));
        }
    }
}

// ---------------------------------------------------------------------------
// Kernel 2: fused energy -> softmax(h) -> sum(t). Round-11 memory structure
// (DPP pair-sum, K prefetch 2 iters / V 1 iter, ping-pong unroll-2). Inner
// math on f32x2 via C vector ops + __builtin_elementwise_fma: gfx950 has
// packed-FP32, so LLVM selects v_pk_{mul,add,fma}_f32 with CORRECT op_sel
// itself (round-13 lesson: hand-written VOP3P asm with defaulted op_sel_hi
// computed hi-halves from lo sources -> silent wrong answers).
// Grid: 2n * 32st(8s) * 2eh * 16tc = 2048 blocks.
// ---------------------------------------------------------------------------
#define ATTN_STEP(KU4, VU4)                                                    \
    {                                                                          \
        f32x2 k2[4], v2[4], p0[4], p1[4];                                      \
        k2[0] = unpk2(KU4.x); k2[1] = unpk2(KU4.y);                            \
        k2[2] = unpk2(KU4.z); k2[3] = unpk2(KU4.w);                            \
        _Pragma("unroll")                                                      \
        for (int j = 0; j < 4; ++j) {                                          \
            const f32x2 x0 = q0_2[j] * k2[j];                                  \
            const f32x2 x1 = q1_2[j] * k2[j];                                  \
            p0[j].x = fexp2(x0.x); p0[j].y = fexp2(x0.y);                      \
            p1[j].x = fexp2(x1.x); p1[j].y = fexp2(x1.y);                      \
        }                                                                      \
        const f32x2 s0 = (p0[0] + p0[1]) + (p0[2] + p0[3]);                    \
        const f32x2 s1 = (p1[0] + p1[1]) + (p1[2] + p1[3]);                    \
        const float rs0 = frcp(pairsum_dpp(s0.x + s0.y));                      \
        const float rs1 = frcp(pairsum_dpp(s1.x + s1.y));                      \
        const f32x2 rb0 = {rs0, rs0};                                          \
        const f32x2 rb1 = {rs1, rs1};                                          \
        v2[0] = unpk2(VU4.x); v2[1] = unpk2(VU4.y);                            \
        v2[2] = unpk2(VU4.z); v2[3] = unpk2(VU4.w);                            \
        _Pragma("unroll")                                                      \
        for (int j = 0; j < 4; ++j) {                                          \
            acc0[j] = __builtin_elementwise_fma(v2[j] * rb0, p0[j], acc0[j]);  \
            acc1[j] = __builtin_elementwise_fma(v2[j] * rb1, p1[j], acc1[j]);  \
        }                                                                      \
    }

__global__ __launch_bounds__(256) void attn_kernel(
    const ushortT* __restrict__ Q,
    const ushortT* __restrict__ K,
    const ushortT* __restrict__ V,
    float* __restrict__ AO)
{
    const int b    = blockIdx.x;
    const int tc   = b & 15;
    const int eh   = (b >> 4) & 1;
    const int st   = (b >> 5) & 31;
    const int n    = b >> 10;
    const int wave = threadIdx.x >> 6;
    const int l    = threadIdx.x & 63;
    const int s0   = st * 8 + wave * 2;
    const int t0   = tc * 16;

    f32x2 q0_2[4], q1_2[4];
    {
        const uint4* qp = (const uint4*)(Q + (size_t)(n * SQL + s0) * EMB + 512 * eh) + l;
        const uint4 qa = qp[0];
        const uint4 qb = qp[128];   // next s row
        q0_2[0] = unpk2(qa.x); q0_2[1] = unpk2(qa.y);
        q0_2[2] = unpk2(qa.z); q0_2[3] = unpk2(qa.w);
        q1_2[0] = unpk2(qb.x); q1_2[1] = unpk2(qb.y);
        q1_2[2] = unpk2(qb.z); q1_2[3] = unpk2(qb.w);
    }

    f32x2 acc0[4], acc1[4];
#pragma unroll
    for (int j = 0; j < 4; ++j) {
        acc0[j] = (f32x2){0.f, 0.f};
        acc1[j] = (f32x2){0.f, 0.f};
    }

    const uint4* kp = (const uint4*)(K + (size_t)(n * SQL + t0) * EMB + 512 * eh) + l;
    const uint4* vp = (const uint4*)(V + (size_t)(n * SQL + t0) * EMB + 512 * eh) + l;

    uint4 ka = kp[0];      // k(t)
    uint4 kb = kp[128];    // k(t+1)
    uint4 va = vp[0];      // v(t)

#pragma unroll
    for (int tt = 0; tt < 16; tt += 2) {
        const uint4 kn2 = kp[256];   // k(t+2)
        const uint4 vb  = vp[128];   // v(t+1)
        ATTN_STEP(ka, va);           // consume t
        const uint4 kn3 = kp[384];   // k(t+3) (tail over-read: safe)
        va = vp[256];                // v(t+2) (tail over-read: safe)
        kp += 256; vp += 256;
        ATTN_STEP(kb, vb);           // consume t+1
        ka = kn2; kb = kn3;
    }

    // element = 512eh + 8l + c  ->  e = 32eh+(l>>1), h = 8(l&1)+c
    // AO channel = h*64 + e = 512(l&1) + 64c + 32eh + (l>>1)
    float* base0 = AO + (size_t)(n * SQL + s0) * EMB + 512 * (l & 1) + 32 * eh + (l >> 1);
    float* base1 = base0 + EMB;
#pragma unroll
    for (int j = 0; j < 4; ++j) {
        atomicAdd(base0 + 64 * (2 * j),     acc0[j].x);
        atomicAdd(base0 + 64 * (2 * j + 1), acc0[j].y);
        atomicAdd(base1 + 64 * (2 * j),     acc1[j].x);
        atomicAdd(base1 + 64 * (2 * j + 1), acc1[j].y);
    }
}

// ---------------------------------------------------------------------------
// Kernel 3: out += AO @ Wob^T via bf16 MFMA. 64r x 128j tile, 512 threads
// (8 waves = 2x4 grid of 32x32 quadrants), k-split 4 -> f32 atomicAdd into
// bias-initialized out. Grid = 8rt * 8jt * 4kc = 256 blocks.
// ---------------------------------------------------------------------------
__global__ __launch_bounds__(512) void proj_kernel(
    const float* __restrict__ AO,
    const ushortT* __restrict__ Wob,
    float* __restrict__ out)
{
    __shared__ ushortT As[64 * 40];
    __shared__ ushortT Bs[128 * 40];

    const int b  = blockIdx.x;
    const int kc = b & 3;
    const int jt = (b >> 2) & 7;
    const int rt = b >> 5;
    const int tid = threadIdx.x;
    const int r0 = rt * 64, j0 = jt * 128, k0 = kc * 256;

    const int w  = tid >> 6;        // 0..7
    const int wr = w >> 2;          // 0..1
    const int wc = w & 3;           // 0..3
    const int l  = tid & 63;
    const int lr = l & 15;
    const int lk = l >> 4;

    f32x4 c00 = {0.f, 0.f, 0.f, 0.f};
    f32x4 c01 = {0.f, 0.f, 0.f, 0.f};
    f32x4 c10 = {0.f, 0.f, 0.f, 0.f};
    f32x4 c11 = {0.f, 0.f, 0.f, 0.f};

    for (int kt = 0; kt < 8; ++kt) {
        const int kb = k0 + kt * 32;
        __syncthreads();
        {
            const int row = tid >> 3;
            const int kq  = tid & 7;
            const float4 a = *(const float4*)&AO[(size_t)(r0 + row) * EMB + kb + kq * 4];
            *(ushort4*)&As[row * 40 + kq * 4] = f2bf4(a);
        }
        {
            const int row = tid >> 2;
            const int ko  = tid & 3;
            const uint4 wv = *(const uint4*)&Wob[(size_t)(j0 + row) * EMB + kb + ko * 8];
            *(uint4*)&Bs[row * 40 + ko * 8] = wv;
        }
        __syncthreads();

        const bf16x8 a0 = *(const bf16x8*)&As[(wr * 32 + lr) * 40 + lk * 8];
        const bf16x8 a1 = *(const bf16x8*)&As[(wr * 32 + 16 + lr) * 40 + lk * 8];
        const bf16x8 b0 = *(const bf16x8*)&Bs[(wc * 32 + lr) * 40 + lk * 8];
        const bf16x8 b1 = *(const bf16x8*)&Bs[(wc * 32 + 16 + lr) * 40 + lk * 8];
        c00 = __builtin_amdgcn_mfma_f32_16x16x32_bf16(a0, b0, c00, 0, 0, 0);
        c01 = __builtin_amdgcn_mfma_f32_16x16x32_bf16(a0, b1, c01, 0, 0, 0);
        c10 = __builtin_amdgcn_mfma_f32_16x16x32_bf16(a1, b0, c10, 0, 0, 0);
        c11 = __builtin_amdgcn_mfma_f32_16x16x32_bf16(a1, b1, c11, 0, 0, 0);
    }

    const int rbase = r0 + wr * 32 + lk * 4;
    const int jbase = j0 + wc * 32 + lr;
#pragma unroll
    for (int e = 0; e < 4; ++e) {
        atomicAdd(&out[(size_t)(rbase + e) * EMB + jbase],           c00[e]);
        atomicAdd(&out[(size_t)(rbase + e) * EMB + jbase + 16],      c01[e]);
        atomicAdd(&out[(size_t)(rbase + 16 + e) * EMB + jbase],      c10[e]);
        atomicAdd(&out[(size_t)(rbase + 16 + e) * EMB + jbase + 16], c11[e]);
    }
}

extern "C" void kernel_launch(void* const* d_in, const int* in_sizes, int n_in,
                              void* d_out, int out_size, void* d_ws, size_t ws_size,
                              hipStream_t stream)
{
    const float* x  = (const float*)d_in[0];
    const float* Wq = (const float*)d_in[1];
    const float* Wk = (const float*)d_in[2];
    const float* Wv = (const float*)d_in[3];
    const float* Wo = (const float*)d_in[4];
    const float* bo = (const float*)d_in[5];

    float* ws = (float*)d_ws;
    ushortT* Q   = (ushortT*)ws;              // 524288 bf16 = 1 MB
    ushortT* K   = (ushortT*)(ws + 262144);   // 1 MB
    ushortT* V   = (ushortT*)(ws + 524288);   // 1 MB
    float*   AO  = ws + 786432;               // 524288 f32 = 2 MB
    ushortT* Wob = (ushortT*)(ws + 1310720);  // 1048576 bf16 = 2 MB

    qkv_kernel<<<256, 256, 0, stream>>>(x, Wq, Wk, Wv, Wo, bo, Q, K, V, AO,
                                        (float*)d_out, Wob);
    attn_kernel<<<2048, 256, 0, stream>>>(Q, K, V, AO);
    proj_kernel<<<256, 512, 0, stream>>>(AO, Wob, (float*)d_out);
}